// Round 6
// baseline (159.666 us; speedup 1.0000x reference)
//
#include <hip/hip_runtime.h>
#include <math.h>

#define BLOCK 256
#define QPT   4      // queries per thread in the values pass
#define CHUNK 512    // max refs staged per LDS chunk (8 KB of float4)

// Rounding-exact helpers: match numpy's mul-then-add rounding exactly.
__device__ __forceinline__ float mul_rn(float a, float b) {
#pragma clang fp contract(off)
    return a * b;
}
__device__ __forceinline__ float add_rn(float a, float b) {
#pragma clang fp contract(off)
    return a + b;
}
__device__ __forceinline__ float sumsq3(float x, float y, float z) {
    return add_rn(add_rn(mul_rn(x, x), mul_rn(y, y)), mul_rn(z, z));
}
__device__ __forceinline__ float med3f(float a, float b, float c) {
    return __builtin_amdgcn_fmed3f(a, b, c);
}
// sq = (||a||^2 + ||b||^2) - 2*dot, dot as BLAS k-order fma chain; the
// -2*dot fold is single-rounded (2*dot exact) => bit-matches the reference.
__device__ __forceinline__ float pair_sq(float a0, float a1, float a2, float an,
                                         float bx, float by, float bz, float bw) {
    const float dot = __builtin_fmaf(a2, bz,
                      __builtin_fmaf(a1, by, mul_rn(a0, bx)));
    return __builtin_fmaf(-2.0f, dot, add_rn(an, bw));
}

// Stage cnt refs (cnt % 4 == 0, start % 4 == 0) into smem as (x,y,z,||b||^2).
__device__ __forceinline__ void stage_chunk(const float* __restrict__ r,
                                            int start, int cnt,
                                            float4* __restrict__ smem) {
    const int t = threadIdx.x;
    if (t < (cnt >> 2)) {
        const float4* p = (const float4*)(r + (size_t)(start + t * 4) * 3);
        const float4 A = p[0], B = p[1], C = p[2];
        smem[t * 4 + 0] = make_float4(A.x, A.y, A.z, sumsq3(A.x, A.y, A.z));
        smem[t * 4 + 1] = make_float4(A.w, B.x, B.y, sumsq3(A.w, B.x, B.y));
        smem[t * 4 + 2] = make_float4(B.z, B.w, C.x, sumsq3(B.z, B.w, C.x));
        smem[t * 4 + 3] = make_float4(C.y, C.z, C.w, sumsq3(C.y, C.z, C.w));
    }
}

// Streaming top-3 VALUES update (exact selection, no arithmetic on values).
__device__ __forceinline__ void val3_push(float& d0, float& d1, float& d2, float v) {
    const float t0 = d0, t1 = d1;
    d0 = fminf(t0, v);
    d1 = med3f(t0, d1, v);
    d2 = med3f(t1, d2, v);
}

// Lexicographic (sq, idx) top-3 insert — matches lax.top_k stability.
__device__ __forceinline__ void lex3_push(float& d0, float& d1, float& d2,
                                          int& i0, int& i1, int& i2,
                                          float sq, int idx) {
    const bool l0 = (sq < d0) || (sq == d0 && idx < i0);
    const bool l1 = (sq < d1) || (sq == d1 && idx < i1);
    const bool l2 = (sq < d2) || (sq == d2 && idx < i2);
    i2 = l1 ? i1 : (l2 ? idx : i2);
    d2 = l1 ? d1 : (l2 ? sq  : d2);
    i1 = l0 ? i0 : (l1 ? idx : i1);
    d1 = l0 ? d0 : (l1 ? sq  : d1);
    i0 = l0 ? idx : i0;
    d0 = l0 ? sq  : d0;
}

// Pass 1: branchless top-3 VALUES per (query, slice). 8 VALU/pair, zero
// control flow in the inner loop. QPT=4, S=64 -> 1024 blocks = 4 blocks/CU
// (16 waves/CU) for latency hiding; LDS broadcast pipe at ~75% of VALU wall.
__global__ __launch_bounds__(BLOCK) void values_kernel(
    const float* __restrict__ q, const float* __restrict__ r,
    float* __restrict__ vcand, int N, int refsPerSlice)
{
    __shared__ float4 smem[CHUNK];
    const int tid = threadIdx.x;
    const int start = blockIdx.y * refsPerSlice;

    float a0[QPT], a1[QPT], a2[QPT], an[QPT];
    float d0[QPT], d1[QPT], d2[QPT];
#pragma unroll
    for (int u = 0; u < QPT; ++u) {
        const int qi = (blockIdx.x * QPT + u) * BLOCK + tid;
        a0[u] = q[qi * 3 + 0];
        a1[u] = q[qi * 3 + 1];
        a2[u] = q[qi * 3 + 2];
        an[u] = sumsq3(a0[u], a1[u], a2[u]);
        d0[u] = __builtin_inff(); d1[u] = __builtin_inff(); d2[u] = __builtin_inff();
    }

    for (int coff = 0; coff < refsPerSlice; coff += CHUNK) {
        const int cnt = min(CHUNK, refsPerSlice - coff);
        __syncthreads();
        stage_chunk(r, start + coff, cnt, smem);
        __syncthreads();
#pragma unroll 2
        for (int j = 0; j < cnt; ++j) {
            const float4 b = smem[j];
#pragma unroll
            for (int u = 0; u < QPT; ++u) {
                const float sq = pair_sq(a0[u], a1[u], a2[u], an[u],
                                         b.x, b.y, b.z, b.w);
                val3_push(d0[u], d1[u], d2[u], sq);
            }
        }
    }

#pragma unroll
    for (int u = 0; u < QPT; ++u) {
        const int qi = (blockIdx.x * QPT + u) * BLOCK + tid;
        float* o = vcand + ((size_t)blockIdx.y * N + qi) * 3;
        o[0] = d0[u]; o[1] = d1[u]; o[2] = d2[u];
    }
}

// Pass 2: thread per query, fully coalesced (consecutive lanes read
// consecutive triples). Loop 1: exact global 3rd-smallest value g2.
// Loop 2: 64-bit mask of slices with slice_min <= g2 — only those can hold
// a global top-3 member (and any slice with min <= g2 does, up to ties),
// so popcount(mask) <= 3 + ties.
__global__ __launch_bounds__(BLOCK) void bound_kernel(
    const float* __restrict__ vcand, float* __restrict__ d2q,
    unsigned long long* __restrict__ msk, int N, int S)
{
    const int qi = blockIdx.x * BLOCK + threadIdx.x;
    float g0 = __builtin_inff(), g1 = __builtin_inff(), g2 = __builtin_inff();
    for (int s = 0; s < S; ++s) {
        const float* c = vcand + ((size_t)s * N + qi) * 3;
        val3_push(g0, g1, g2, c[0]);
        val3_push(g0, g1, g2, c[1]);
        val3_push(g0, g1, g2, c[2]);
    }
    unsigned long long m = 0;
    for (int s = 0; s < S; ++s) {
        const float sd0 = vcand[((size_t)s * N + qi) * 3];
        if (sd0 <= g2) m |= (1ull << s);
    }
    d2q[qi] = g2;
    msk[qi] = m;
}

// Pass 3: ONE WAVE PER QUERY. Reads two wave-uniform scalars (d2, mask) and
// rescans only the masked slices (~2.5 of 64) with lane-coalesced loads of
// the L2-resident ref array. Per-lane strict-< top-3 (ascending-idx stream)
// then a lexicographic butterfly merge reproduces lax.top_k exactly.
__global__ __launch_bounds__(BLOCK) void rescan_kernel(
    const float* __restrict__ q, const float* __restrict__ r,
    const float* __restrict__ d2q, const unsigned long long* __restrict__ msk,
    const float* __restrict__ flow, float* __restrict__ out,
    int N, int refsPerSlice)
{
    const int lane = threadIdx.x & 63;
    const int qi   = blockIdx.x * (BLOCK / 64) + (threadIdx.x >> 6);

    const float a0 = q[qi * 3 + 0];
    const float a1 = q[qi * 3 + 1];
    const float a2 = q[qi * 3 + 2];
    const float an = sumsq3(a0, a1, a2);

    unsigned long long mask = msk[qi];
    (void)d2q;  // bound value implicit in mask; kept for debugging

    float d0 = __builtin_inff(), d1 = __builtin_inff(), d2 = __builtin_inff();
    int   i0 = 0x7fffffff, i1 = 0x7fffffff, i2 = 0x7fffffff;
    const int K = refsPerSlice >> 6;     // refs per lane per slice

    while (mask) {
        const int s = (int)__builtin_ctzll(mask);
        mask &= mask - 1;
        const int base = s * refsPerSlice;
        for (int k = 0; k < K; ++k) {
            const int idx = base + lane + (k << 6);   // ascending per lane
            const float b0 = r[3 * idx + 0];
            const float b1 = r[3 * idx + 1];
            const float b2 = r[3 * idx + 2];
            const float bw = sumsq3(b0, b1, b2);
            const float sq = pair_sq(a0, a1, a2, an, b0, b1, b2, bw);
            const bool c0 = sq < d0;
            const bool c1 = sq < d1;
            const bool c2 = sq < d2;
            i2 = c1 ? i1 : (c2 ? idx : i2);
            d2 = c1 ? d1 : (c2 ? sq  : d2);
            i1 = c0 ? i0 : (c1 ? idx : i1);
            d1 = c0 ? d0 : (c1 ? sq  : d1);
            i0 = c0 ? idx : i0;
            d0 = c0 ? sq  : d0;
        }
    }

    // lexicographic butterfly merge across the 64 lanes
#pragma unroll
    for (int m = 1; m < 64; m <<= 1) {
        const float e0 = __shfl_xor(d0, m);
        const float e1 = __shfl_xor(d1, m);
        const float e2 = __shfl_xor(d2, m);
        const int   j0 = __shfl_xor(i0, m);
        const int   j1 = __shfl_xor(i1, m);
        const int   j2 = __shfl_xor(i2, m);
        lex3_push(d0, d1, d2, i0, i1, i2, e0, j0);
        lex3_push(d0, d1, d2, i0, i1, i2, e1, j1);
        lex3_push(d0, d1, d2, i0, i1, i2, e2, j2);
    }

    // epilogue (rounding-exact, matches reference op order)
    if (lane == 0) {
        const float t0 = sqrtf(fmaxf(d0, 1e-12f));
        const float t1 = sqrtf(fmaxf(d1, 1e-12f));
        const float t2 = sqrtf(fmaxf(d2, 1e-12f));
        const float w0r = 1.0f / add_rn(t0, 1e-8f);
        const float w1r = 1.0f / add_rn(t1, 1e-8f);
        const float w2r = 1.0f / add_rn(t2, 1e-8f);
        const float wsum = add_rn(add_rn(w0r, w1r), w2r);
        const float w0 = w0r / wsum;
        const float w1 = w1r / wsum;
        const float w2 = w2r / wsum;

        const float f00 = flow[3 * i0 + 0], f01 = flow[3 * i0 + 1], f02 = flow[3 * i0 + 2];
        const float f10 = flow[3 * i1 + 0], f11 = flow[3 * i1 + 1], f12 = flow[3 * i1 + 2];
        const float f20 = flow[3 * i2 + 0], f21 = flow[3 * i2 + 1], f22 = flow[3 * i2 + 2];

        out[qi * 3 + 0] = add_rn(add_rn(mul_rn(w0, f00), mul_rn(w1, f10)), mul_rn(w2, f20));
        out[qi * 3 + 1] = add_rn(add_rn(mul_rn(w0, f01), mul_rn(w1, f11)), mul_rn(w2, f21));
        out[qi * 3 + 2] = add_rn(add_rn(mul_rn(w0, f02), mul_rn(w1, f12)), mul_rn(w2, f22));
    }
}

extern "C" void kernel_launch(void* const* d_in, const int* in_sizes, int n_in,
                              void* d_out, int out_size, void* d_ws, size_t ws_size,
                              hipStream_t stream) {
    const float* q    = (const float*)d_in[0];
    const float* r    = (const float*)d_in[1];
    const float* flow = (const float*)d_in[2];
    // d_in[3] is k (==3), hard-coded.

    const int N = in_sizes[0] / 3;
    const int M = in_sizes[1] / 3;

    // ws layout: [vcand: S*N*3 f][d2q: N f][msk: N u64]
    const size_t tail = (size_t)N * sizeof(float) + (size_t)N * sizeof(unsigned long long);
    int S = 64;
    while (S > 8 && (size_t)S * N * 3 * sizeof(float) + tail > ws_size) S >>= 1;
    const int refsPerSlice = M / S;

    float* vcand = (float*)d_ws;
    float* d2q   = (float*)((char*)d_ws + (size_t)S * N * 3 * sizeof(float));
    unsigned long long* msk = (unsigned long long*)(d2q + N);

    dim3 grid1(N / (BLOCK * QPT), S);
    values_kernel<<<grid1, BLOCK, 0, stream>>>(q, r, vcand, N, refsPerSlice);
    bound_kernel<<<N / BLOCK, BLOCK, 0, stream>>>(vcand, d2q, msk, N, S);
    rescan_kernel<<<N / (BLOCK / 64), BLOCK, 0, stream>>>(
        q, r, d2q, msk, flow, (float*)d_out, N, refsPerSlice);
}

// Round 7
// 128.655 us; speedup vs baseline: 1.2410x; 1.2410x over previous
//
#include <hip/hip_runtime.h>
#include <math.h>

#define BLOCK 256
#define QPT   4      // queries per thread in the values pass
#define CHUNK 512    // max refs staged per LDS chunk (8 KB of float4)
#define S     64     // slices == wave width (one ballot bit per slice)

// Rounding-exact helpers: match numpy's mul-then-add rounding exactly.
__device__ __forceinline__ float mul_rn(float a, float b) {
#pragma clang fp contract(off)
    return a * b;
}
__device__ __forceinline__ float add_rn(float a, float b) {
#pragma clang fp contract(off)
    return a + b;
}
__device__ __forceinline__ float sumsq3(float x, float y, float z) {
    return add_rn(add_rn(mul_rn(x, x), mul_rn(y, y)), mul_rn(z, z));
}
__device__ __forceinline__ float med3f(float a, float b, float c) {
    return __builtin_amdgcn_fmed3f(a, b, c);
}
// sq = (||a||^2 + ||b||^2) - 2*dot, dot as BLAS k-order fma chain; the
// -2*dot fold is single-rounded (2*dot exact) => bit-matches the reference.
__device__ __forceinline__ float pair_sq(float a0, float a1, float a2, float an,
                                         float bx, float by, float bz, float bw) {
    const float dot = __builtin_fmaf(a2, bz,
                      __builtin_fmaf(a1, by, mul_rn(a0, bx)));
    return __builtin_fmaf(-2.0f, dot, add_rn(an, bw));
}

// In-place top-3 VALUES update: write order d2 <- d1 <- d0 needs NO temp
// copies (old d1/d0 still live when read). 3 VALU, zero v_movs.
__device__ __forceinline__ void val3_push(float& d0, float& d1, float& d2, float v) {
    d2 = med3f(d1, d2, v);
    d1 = med3f(d0, d1, v);
    d0 = fminf(d0, v);
}

// Lexicographic (sq, idx) top-3 insert — matches lax.top_k stability.
__device__ __forceinline__ void lex3_push(float& d0, float& d1, float& d2,
                                          int& i0, int& i1, int& i2,
                                          float sq, int idx) {
    const bool l0 = (sq < d0) || (sq == d0 && idx < i0);
    const bool l1 = (sq < d1) || (sq == d1 && idx < i1);
    const bool l2 = (sq < d2) || (sq == d2 && idx < i2);
    i2 = l1 ? i1 : (l2 ? idx : i2);
    d2 = l1 ? d1 : (l2 ? sq  : d2);
    i1 = l0 ? i0 : (l1 ? idx : i1);
    d1 = l0 ? d0 : (l1 ? sq  : d1);
    i0 = l0 ? idx : i0;
    d0 = l0 ? sq  : d0;
}

// Stage cnt refs (cnt % 4 == 0, start % 4 == 0) into smem as (x,y,z,||b||^2).
__device__ __forceinline__ void stage_chunk(const float* __restrict__ r,
                                            int start, int cnt,
                                            float4* __restrict__ smem) {
    const int t = threadIdx.x;
    if (t < (cnt >> 2)) {
        const float4* p = (const float4*)(r + (size_t)(start + t * 4) * 3);
        const float4 A = p[0], B = p[1], C = p[2];
        smem[t * 4 + 0] = make_float4(A.x, A.y, A.z, sumsq3(A.x, A.y, A.z));
        smem[t * 4 + 1] = make_float4(A.w, B.x, B.y, sumsq3(A.w, B.x, B.y));
        smem[t * 4 + 2] = make_float4(B.z, B.w, C.x, sumsq3(B.z, B.w, C.x));
        smem[t * 4 + 3] = make_float4(C.y, C.z, C.w, sumsq3(C.y, C.z, C.w));
    }
}

// Pass 1: branchless top-3 VALUES per (query, slice). 8 VALU/pair, zero
// control flow in the inner loop. __launch_bounds__(256,4) caps VGPR at 128
// so the ~45 live registers fit WITHOUT rematerialization (VGPR=32 in R5
// caused ~2x instruction bloat). Output layout is TRANSPOSED [qi][s][3]:
// scattered 768B-stride stores are posted & hidden under the VALU-bound
// scan, buying a fully coalesced read in pass 2.
__global__ __launch_bounds__(BLOCK, 4) void values_kernel(
    const float* __restrict__ q, const float* __restrict__ r,
    float* __restrict__ vcandT, int N, int refsPerSlice)
{
    __shared__ float4 smem[CHUNK];
    const int tid = threadIdx.x;
    const int s   = blockIdx.y;
    const int start = s * refsPerSlice;

    float a0[QPT], a1[QPT], a2[QPT], an[QPT];
    float d0[QPT], d1[QPT], d2[QPT];
#pragma unroll
    for (int u = 0; u < QPT; ++u) {
        const int qi = (blockIdx.x * QPT + u) * BLOCK + tid;
        a0[u] = q[qi * 3 + 0];
        a1[u] = q[qi * 3 + 1];
        a2[u] = q[qi * 3 + 2];
        an[u] = sumsq3(a0[u], a1[u], a2[u]);
        d0[u] = __builtin_inff(); d1[u] = __builtin_inff(); d2[u] = __builtin_inff();
    }

    for (int coff = 0; coff < refsPerSlice; coff += CHUNK) {
        const int cnt = min(CHUNK, refsPerSlice - coff);
        __syncthreads();
        stage_chunk(r, start + coff, cnt, smem);
        __syncthreads();
#pragma unroll 4
        for (int j = 0; j < cnt; ++j) {
            const float4 b = smem[j];
#pragma unroll
            for (int u = 0; u < QPT; ++u) {
                const float sq = pair_sq(a0[u], a1[u], a2[u], an[u],
                                         b.x, b.y, b.z, b.w);
                val3_push(d0[u], d1[u], d2[u], sq);
            }
        }
    }

#pragma unroll
    for (int u = 0; u < QPT; ++u) {
        const int qi = (blockIdx.x * QPT + u) * BLOCK + tid;
        float* o = vcandT + ((size_t)qi * S + s) * 3;
        o[0] = d0[u]; o[1] = d1[u]; o[2] = d2[u];
    }
}

// Pass 2: ONE WAVE PER QUERY, all in-register:
//  A) lane s reads slice s's value triple — COALESCED (768B per wave, the
//     transposed layout) — and butterfly-reduces the exact global top-3
//     values -> g2.
//  B) ballot(slice_d0 <= g2) = mask of slices that can contain a global
//     top-3 member (slice min <= member value <= g2); popcount <= 3 + ties.
//     Lanes cooperatively rescan only those slices with lane-coalesced,
//     L2-resident loads of r; per-lane strict-< top-3 (ascending-idx
//     stream) then a lexicographic butterfly merge == lax.top_k exactly.
//  C) lane 0: rounding-exact weights + flow gather + store.
__global__ __launch_bounds__(BLOCK, 4) void rescan_kernel(
    const float* __restrict__ q, const float* __restrict__ r,
    const float* __restrict__ vcandT, const float* __restrict__ flow,
    float* __restrict__ out, int N, int refsPerSlice)
{
    const int lane = threadIdx.x & 63;
    const int qi   = blockIdx.x * (BLOCK / 64) + (threadIdx.x >> 6);

    const float a0 = q[qi * 3 + 0];
    const float a1 = q[qi * 3 + 1];
    const float a2 = q[qi * 3 + 2];
    const float an = sumsq3(a0, a1, a2);

    // --- A: coalesced triple load + butterfly value-reduce ---
    const float* c = vcandT + ((size_t)qi * S + lane) * 3;
    const float v0 = c[0], v1 = c[1], v2 = c[2];
    const float sd0 = v0;
    float g0 = v0, g1 = v1, g2 = v2;       // lane-local triple is sorted
#pragma unroll
    for (int m = 1; m < 64; m <<= 1) {
        const float e0 = __shfl_xor(g0, m);
        const float e1 = __shfl_xor(g1, m);
        const float e2 = __shfl_xor(g2, m);
        val3_push(g0, g1, g2, e0);
        val3_push(g0, g1, g2, e1);
        val3_push(g0, g1, g2, e2);
    }

    unsigned long long mask = __ballot(sd0 <= g2);

    // --- B: cooperative rescan of contributing slices ---
    float d0 = __builtin_inff(), d1 = __builtin_inff(), d2 = __builtin_inff();
    int   i0 = 0x7fffffff, i1 = 0x7fffffff, i2 = 0x7fffffff;
    const int K = refsPerSlice >> 6;       // refs per lane per slice

    while (mask) {
        const int s = (int)__builtin_ctzll(mask);
        mask &= mask - 1;
        const int base = s * refsPerSlice;
        for (int k = 0; k < K; ++k) {
            const int idx = base + lane + (k << 6);   // ascending per lane
            const float b0 = r[3 * idx + 0];
            const float b1 = r[3 * idx + 1];
            const float b2 = r[3 * idx + 2];
            const float bw = sumsq3(b0, b1, b2);
            const float sq = pair_sq(a0, a1, a2, an, b0, b1, b2, bw);
            const bool c0 = sq < d0;
            const bool c1 = sq < d1;
            const bool c2 = sq < d2;
            i2 = c1 ? i1 : (c2 ? idx : i2);
            d2 = c1 ? d1 : (c2 ? sq  : d2);
            i1 = c0 ? i0 : (c1 ? idx : i1);
            d1 = c0 ? d0 : (c1 ? sq  : d1);
            i0 = c0 ? idx : i0;
            d0 = c0 ? sq  : d0;
        }
    }

    // lexicographic butterfly merge across the 64 lanes
#pragma unroll
    for (int m = 1; m < 64; m <<= 1) {
        const float e0 = __shfl_xor(d0, m);
        const float e1 = __shfl_xor(d1, m);
        const float e2 = __shfl_xor(d2, m);
        const int   j0 = __shfl_xor(i0, m);
        const int   j1 = __shfl_xor(i1, m);
        const int   j2 = __shfl_xor(i2, m);
        lex3_push(d0, d1, d2, i0, i1, i2, e0, j0);
        lex3_push(d0, d1, d2, i0, i1, i2, e1, j1);
        lex3_push(d0, d1, d2, i0, i1, i2, e2, j2);
    }

    // --- C: epilogue (rounding-exact, matches reference op order) ---
    if (lane == 0) {
        const float t0 = sqrtf(fmaxf(d0, 1e-12f));
        const float t1 = sqrtf(fmaxf(d1, 1e-12f));
        const float t2 = sqrtf(fmaxf(d2, 1e-12f));
        const float w0r = 1.0f / add_rn(t0, 1e-8f);
        const float w1r = 1.0f / add_rn(t1, 1e-8f);
        const float w2r = 1.0f / add_rn(t2, 1e-8f);
        const float wsum = add_rn(add_rn(w0r, w1r), w2r);
        const float w0 = w0r / wsum;
        const float w1 = w1r / wsum;
        const float w2 = w2r / wsum;

        const float f00 = flow[3 * i0 + 0], f01 = flow[3 * i0 + 1], f02 = flow[3 * i0 + 2];
        const float f10 = flow[3 * i1 + 0], f11 = flow[3 * i1 + 1], f12 = flow[3 * i1 + 2];
        const float f20 = flow[3 * i2 + 0], f21 = flow[3 * i2 + 1], f22 = flow[3 * i2 + 2];

        out[qi * 3 + 0] = add_rn(add_rn(mul_rn(w0, f00), mul_rn(w1, f10)), mul_rn(w2, f20));
        out[qi * 3 + 1] = add_rn(add_rn(mul_rn(w0, f01), mul_rn(w1, f11)), mul_rn(w2, f21));
        out[qi * 3 + 2] = add_rn(add_rn(mul_rn(w0, f02), mul_rn(w1, f12)), mul_rn(w2, f22));
    }
}

extern "C" void kernel_launch(void* const* d_in, const int* in_sizes, int n_in,
                              void* d_out, int out_size, void* d_ws, size_t ws_size,
                              hipStream_t stream) {
    const float* q    = (const float*)d_in[0];
    const float* r    = (const float*)d_in[1];
    const float* flow = (const float*)d_in[2];
    // d_in[3] is k (==3), hard-coded.

    const int N = in_sizes[0] / 3;
    const int M = in_sizes[1] / 3;

    // ws layout: [vcandT: N*S*3 floats], transposed [qi][s][3]
    const int refsPerSlice = M / S;
    float* vcandT = (float*)d_ws;
    (void)ws_size;

    dim3 grid1(N / (BLOCK * QPT), S);
    values_kernel<<<grid1, BLOCK, 0, stream>>>(q, r, vcandT, N, refsPerSlice);

    rescan_kernel<<<N / (BLOCK / 64), BLOCK, 0, stream>>>(
        q, r, vcandT, flow, (float*)d_out, N, refsPerSlice);
}

// Round 8
// 113.217 us; speedup vs baseline: 1.4103x; 1.1364x over previous
//
#include <hip/hip_runtime.h>
#include <math.h>

#define BLOCK 256
#define QPT   8      // queries per thread in the values pass
#define CHUNK 512    // max refs staged per LDS chunk (8 KB of float4)
#define S     64     // slices == wave width (one ballot bit per slice)

// Rounding-exact helpers: match numpy's mul-then-add rounding exactly.
__device__ __forceinline__ float mul_rn(float a, float b) {
#pragma clang fp contract(off)
    return a * b;
}
__device__ __forceinline__ float add_rn(float a, float b) {
#pragma clang fp contract(off)
    return a + b;
}
__device__ __forceinline__ float sumsq3(float x, float y, float z) {
    return add_rn(add_rn(mul_rn(x, x), mul_rn(y, y)), mul_rn(z, z));
}
__device__ __forceinline__ float med3f(float a, float b, float c) {
    return __builtin_amdgcn_fmed3f(a, b, c);
}
// sq = (||a||^2 + ||b||^2) - 2*dot, dot as BLAS k-order fma chain; the
// -2*dot fold is single-rounded (2*dot exact) => bit-matches the reference.
__device__ __forceinline__ float pair_sq(float a0, float a1, float a2, float an,
                                         float bx, float by, float bz, float bw) {
    const float dot = __builtin_fmaf(a2, bz,
                      __builtin_fmaf(a1, by, mul_rn(a0, bx)));
    return __builtin_fmaf(-2.0f, dot, add_rn(an, bw));
}

// In-place top-3 VALUES update: write order d2 <- d1 <- d0 needs NO temps.
__device__ __forceinline__ void val3_push(float& d0, float& d1, float& d2, float v) {
    d2 = med3f(d1, d2, v);
    d1 = med3f(d0, d1, v);
    d0 = fminf(d0, v);
}

// Lexicographic (sq, idx) top-3 insert — matches lax.top_k stability.
__device__ __forceinline__ void lex3_push(float& d0, float& d1, float& d2,
                                          int& i0, int& i1, int& i2,
                                          float sq, int idx) {
    const bool l0 = (sq < d0) || (sq == d0 && idx < i0);
    const bool l1 = (sq < d1) || (sq == d1 && idx < i1);
    const bool l2 = (sq < d2) || (sq == d2 && idx < i2);
    i2 = l1 ? i1 : (l2 ? idx : i2);
    d2 = l1 ? d1 : (l2 ? sq  : d2);
    i1 = l0 ? i0 : (l1 ? idx : i1);
    d1 = l0 ? d0 : (l1 ? sq  : d1);
    i0 = l0 ? idx : i0;
    d0 = l0 ? sq  : d0;
}

// Stage cnt refs (cnt % 4 == 0, start % 4 == 0) into smem as (x,y,z,||b||^2).
__device__ __forceinline__ void stage_chunk(const float* __restrict__ r,
                                            int start, int cnt,
                                            float4* __restrict__ smem) {
    const int t = threadIdx.x;
    if (t < (cnt >> 2)) {
        const float4* p = (const float4*)(r + (size_t)(start + t * 4) * 3);
        const float4 A = p[0], B = p[1], C = p[2];
        smem[t * 4 + 0] = make_float4(A.x, A.y, A.z, sumsq3(A.x, A.y, A.z));
        smem[t * 4 + 1] = make_float4(A.w, B.x, B.y, sumsq3(A.w, B.x, B.y));
        smem[t * 4 + 2] = make_float4(B.z, B.w, C.x, sumsq3(B.z, B.w, C.x));
        smem[t * 4 + 3] = make_float4(C.y, C.z, C.w, sumsq3(C.y, C.z, C.w));
    }
}

// Pass 1: per (query, slice) MINIMUM sq only — 6 VALU/pair (5-op exact
// pair_sq + 1 fminf), zero control flow, 8 independent min-chains per
// thread for ILP. Why min suffices: with m(1)<=m(2)<=m(3) the three
// smallest slice-mins (3 distinct points!), true g2 <= m(3), and every
// top-3 member's slice has min <= g2 <= m(3) — so pass 2 can build its
// slice mask from mins alone. Output TRANSPOSED smin[qi][s] so pass 2
// reads 256 B/wave coalesced.
__global__ __launch_bounds__(BLOCK, 2) void values_kernel(
    const float* __restrict__ q, const float* __restrict__ r,
    float* __restrict__ smin, int N, int refsPerSlice)
{
    __shared__ float4 smem[CHUNK];
    const int tid = threadIdx.x;
    const int s   = blockIdx.y;
    const int start = s * refsPerSlice;

    float a0[QPT], a1[QPT], a2[QPT], an[QPT], d0[QPT];
#pragma unroll
    for (int u = 0; u < QPT; ++u) {
        const int qi = (blockIdx.x * QPT + u) * BLOCK + tid;
        a0[u] = q[qi * 3 + 0];
        a1[u] = q[qi * 3 + 1];
        a2[u] = q[qi * 3 + 2];
        an[u] = sumsq3(a0[u], a1[u], a2[u]);
        d0[u] = __builtin_inff();
    }

    for (int coff = 0; coff < refsPerSlice; coff += CHUNK) {
        const int cnt = min(CHUNK, refsPerSlice - coff);
        __syncthreads();
        stage_chunk(r, start + coff, cnt, smem);
        __syncthreads();
#pragma unroll 4
        for (int j = 0; j < cnt; ++j) {
            const float4 b = smem[j];
#pragma unroll
            for (int u = 0; u < QPT; ++u) {
                const float sq = pair_sq(a0[u], a1[u], a2[u], an[u],
                                         b.x, b.y, b.z, b.w);
                d0[u] = fminf(d0[u], sq);
            }
        }
    }

#pragma unroll
    for (int u = 0; u < QPT; ++u) {
        const int qi = (blockIdx.x * QPT + u) * BLOCK + tid;
        smin[(size_t)qi * S + s] = d0[u];
    }
}

// Pass 2: ONE WAVE PER QUERY, all in-register:
//  A) lane s reads slice s's min (coalesced 256 B/wave); butterfly-reduce
//     the 3 smallest slice-mins -> ub = 3rd-smallest (>= true g2).
//  B) mask = ballot(slice_min <= ub) covers every slice containing a true
//     top-3 member; popcount ~3-4. Lanes cooperatively rescan those slices
//     with lane-coalesced loads; per-lane strict-< top-3 (ascending-idx
//     stream) then a lexicographic butterfly merge == lax.top_k exactly.
//  C) lane 0: rounding-exact weights + flow gather + store.
__global__ __launch_bounds__(BLOCK, 4) void rescan_kernel(
    const float* __restrict__ q, const float* __restrict__ r,
    const float* __restrict__ smin, const float* __restrict__ flow,
    float* __restrict__ out, int N, int refsPerSlice)
{
    const int lane = threadIdx.x & 63;
    const int qi   = blockIdx.x * (BLOCK / 64) + (threadIdx.x >> 6);

    const float a0 = q[qi * 3 + 0];
    const float a1 = q[qi * 3 + 1];
    const float a2 = q[qi * 3 + 2];
    const float an = sumsq3(a0, a1, a2);

    // --- A: coalesced min load + butterfly 3-smallest reduce ---
    const float v = smin[(size_t)qi * S + lane];
    float g0 = v, g1 = __builtin_inff(), g2 = __builtin_inff();
#pragma unroll
    for (int m = 1; m < 64; m <<= 1) {
        const float e0 = __shfl_xor(g0, m);
        const float e1 = __shfl_xor(g1, m);
        const float e2 = __shfl_xor(g2, m);
        val3_push(g0, g1, g2, e0);
        val3_push(g0, g1, g2, e1);
        val3_push(g0, g1, g2, e2);
    }

    unsigned long long mask = __ballot(v <= g2);

    // --- B: cooperative rescan of contributing slices ---
    float d0 = __builtin_inff(), d1 = __builtin_inff(), d2 = __builtin_inff();
    int   i0 = 0x7fffffff, i1 = 0x7fffffff, i2 = 0x7fffffff;
    const int K = refsPerSlice >> 6;       // refs per lane per slice

    while (mask) {
        const int s = (int)__builtin_ctzll(mask);
        mask &= mask - 1;
        const int base = s * refsPerSlice;
        for (int k = 0; k < K; ++k) {
            const int idx = base + lane + (k << 6);   // ascending per lane
            const float b0 = r[3 * idx + 0];
            const float b1 = r[3 * idx + 1];
            const float b2 = r[3 * idx + 2];
            const float bw = sumsq3(b0, b1, b2);
            const float sq = pair_sq(a0, a1, a2, an, b0, b1, b2, bw);
            const bool c0 = sq < d0;
            const bool c1 = sq < d1;
            const bool c2 = sq < d2;
            i2 = c1 ? i1 : (c2 ? idx : i2);
            d2 = c1 ? d1 : (c2 ? sq  : d2);
            i1 = c0 ? i0 : (c1 ? idx : i1);
            d1 = c0 ? d0 : (c1 ? sq  : d1);
            i0 = c0 ? idx : i0;
            d0 = c0 ? sq  : d0;
        }
    }

    // lexicographic butterfly merge across the 64 lanes
#pragma unroll
    for (int m = 1; m < 64; m <<= 1) {
        const float e0 = __shfl_xor(d0, m);
        const float e1 = __shfl_xor(d1, m);
        const float e2 = __shfl_xor(d2, m);
        const int   j0 = __shfl_xor(i0, m);
        const int   j1 = __shfl_xor(i1, m);
        const int   j2 = __shfl_xor(i2, m);
        lex3_push(d0, d1, d2, i0, i1, i2, e0, j0);
        lex3_push(d0, d1, d2, i0, i1, i2, e1, j1);
        lex3_push(d0, d1, d2, i0, i1, i2, e2, j2);
    }

    // --- C: epilogue (rounding-exact, matches reference op order) ---
    if (lane == 0) {
        const float t0 = sqrtf(fmaxf(d0, 1e-12f));
        const float t1 = sqrtf(fmaxf(d1, 1e-12f));
        const float t2 = sqrtf(fmaxf(d2, 1e-12f));
        const float w0r = 1.0f / add_rn(t0, 1e-8f);
        const float w1r = 1.0f / add_rn(t1, 1e-8f);
        const float w2r = 1.0f / add_rn(t2, 1e-8f);
        const float wsum = add_rn(add_rn(w0r, w1r), w2r);
        const float w0 = w0r / wsum;
        const float w1 = w1r / wsum;
        const float w2 = w2r / wsum;

        const float f00 = flow[3 * i0 + 0], f01 = flow[3 * i0 + 1], f02 = flow[3 * i0 + 2];
        const float f10 = flow[3 * i1 + 0], f11 = flow[3 * i1 + 1], f12 = flow[3 * i1 + 2];
        const float f20 = flow[3 * i2 + 0], f21 = flow[3 * i2 + 1], f22 = flow[3 * i2 + 2];

        out[qi * 3 + 0] = add_rn(add_rn(mul_rn(w0, f00), mul_rn(w1, f10)), mul_rn(w2, f20));
        out[qi * 3 + 1] = add_rn(add_rn(mul_rn(w0, f01), mul_rn(w1, f11)), mul_rn(w2, f21));
        out[qi * 3 + 2] = add_rn(add_rn(mul_rn(w0, f02), mul_rn(w1, f12)), mul_rn(w2, f22));
    }
}

extern "C" void kernel_launch(void* const* d_in, const int* in_sizes, int n_in,
                              void* d_out, int out_size, void* d_ws, size_t ws_size,
                              hipStream_t stream) {
    const float* q    = (const float*)d_in[0];
    const float* r    = (const float*)d_in[1];
    const float* flow = (const float*)d_in[2];
    // d_in[3] is k (==3), hard-coded.

    const int N = in_sizes[0] / 3;
    const int M = in_sizes[1] / 3;

    // ws layout: [smin: N*S floats], transposed [qi][s]
    const int refsPerSlice = M / S;
    float* smin = (float*)d_ws;
    (void)ws_size;

    dim3 grid1(N / (BLOCK * QPT), S);
    values_kernel<<<grid1, BLOCK, 0, stream>>>(q, r, smin, N, refsPerSlice);

    rescan_kernel<<<N / (BLOCK / 64), BLOCK, 0, stream>>>(
        q, r, smin, flow, (float*)d_out, N, refsPerSlice);
}

// Round 9
// 110.853 us; speedup vs baseline: 1.4403x; 1.0213x over previous
//
#include <hip/hip_runtime.h>
#include <math.h>

#define BLOCK 256
#define QPT   8      // queries per thread in the values pass
#define CHUNK 512    // max refs staged per LDS chunk (8 KB of float4)
#define S     64     // slices == wave width (one ballot bit per slice)
#define DELTA 0.05f  // conservative slack for deferred-an slice mins (see below)

// Rounding-exact helpers: match numpy's mul-then-add rounding exactly.
__device__ __forceinline__ float mul_rn(float a, float b) {
#pragma clang fp contract(off)
    return a * b;
}
__device__ __forceinline__ float add_rn(float a, float b) {
#pragma clang fp contract(off)
    return a + b;
}
__device__ __forceinline__ float sumsq3(float x, float y, float z) {
    return add_rn(add_rn(mul_rn(x, x), mul_rn(y, y)), mul_rn(z, z));
}
__device__ __forceinline__ float med3f(float a, float b, float c) {
    return __builtin_amdgcn_fmed3f(a, b, c);
}
// EXACT sq = (||a||^2 + ||b||^2) - 2*dot — bit-matches the reference
// (used in the rescan where indices are selected).
__device__ __forceinline__ float pair_sq(float a0, float a1, float a2, float an,
                                         float bx, float by, float bz, float bw) {
    const float dot = __builtin_fmaf(a2, bz,
                      __builtin_fmaf(a1, by, mul_rn(a0, bx)));
    return __builtin_fmaf(-2.0f, dot, add_rn(an, bw));
}

// In-place top-3 VALUES update: write order d2 <- d1 <- d0 needs NO temps.
__device__ __forceinline__ void val3_push(float& d0, float& d1, float& d2, float v) {
    d2 = med3f(d1, d2, v);
    d1 = med3f(d0, d1, v);
    d0 = fminf(d0, v);
}

// Lexicographic (sq, idx) top-3 insert — matches lax.top_k stability.
__device__ __forceinline__ void lex3_push(float& d0, float& d1, float& d2,
                                          int& i0, int& i1, int& i2,
                                          float sq, int idx) {
    const bool l0 = (sq < d0) || (sq == d0 && idx < i0);
    const bool l1 = (sq < d1) || (sq == d1 && idx < i1);
    const bool l2 = (sq < d2) || (sq == d2 && idx < i2);
    i2 = l1 ? i1 : (l2 ? idx : i2);
    d2 = l1 ? d1 : (l2 ? sq  : d2);
    i1 = l0 ? i0 : (l1 ? idx : i1);
    d1 = l0 ? d0 : (l1 ? sq  : d1);
    i0 = l0 ? idx : i0;
    d0 = l0 ? sq  : d0;
}

// Stage cnt refs (cnt % 4 == 0, start % 4 == 0) into smem as (x,y,z,||b||^2).
__device__ __forceinline__ void stage_chunk(const float* __restrict__ r,
                                            int start, int cnt,
                                            float4* __restrict__ smem) {
    const int t = threadIdx.x;
    if (t < (cnt >> 2)) {
        const float4* p = (const float4*)(r + (size_t)(start + t * 4) * 3);
        const float4 A = p[0], B = p[1], C = p[2];
        smem[t * 4 + 0] = make_float4(A.x, A.y, A.z, sumsq3(A.x, A.y, A.z));
        smem[t * 4 + 1] = make_float4(A.w, B.x, B.y, sumsq3(A.w, B.x, B.y));
        smem[t * 4 + 2] = make_float4(B.z, B.w, C.x, sumsq3(B.z, B.w, C.x));
        smem[t * 4 + 3] = make_float4(C.y, C.z, C.w, sumsq3(C.y, C.z, C.w));
    }
}

// Pass 1: per (query, slice) approximate min of sq, with `an` DEFERRED out
// of the inner loop:  min_j[(an+bw)-2dot] = an + min_j[bw-2dot] (+O(5e-3)
// fp32 rounding drift). Hot loop is 5 VALU/pair: dot (3 fma-chain ops),
// fma(-2,dot,bw), v_min. The drift is absorbed by DELTA in pass 2's mask
// threshold — mins only gate WHICH slices get exactly rescanned, so slack
// can only ADD candidate slices, never change the final answer.
__global__ __launch_bounds__(BLOCK, 2) void values_kernel(
    const float* __restrict__ q, const float* __restrict__ r,
    float* __restrict__ smin, int N, int refsPerSlice)
{
    __shared__ float4 smem[CHUNK];
    const int tid = threadIdx.x;
    const int s   = blockIdx.y;
    const int start = s * refsPerSlice;

    float a0[QPT], a1[QPT], a2[QPT], an[QPT], d0[QPT];
#pragma unroll
    for (int u = 0; u < QPT; ++u) {
        const int qi = (blockIdx.x * QPT + u) * BLOCK + tid;
        a0[u] = q[qi * 3 + 0];
        a1[u] = q[qi * 3 + 1];
        a2[u] = q[qi * 3 + 2];
        an[u] = sumsq3(a0[u], a1[u], a2[u]);
        d0[u] = __builtin_inff();
    }

    for (int coff = 0; coff < refsPerSlice; coff += CHUNK) {
        const int cnt = min(CHUNK, refsPerSlice - coff);
        __syncthreads();
        stage_chunk(r, start + coff, cnt, smem);
        __syncthreads();
#pragma unroll 4
        for (int j = 0; j < cnt; ++j) {
            const float4 b = smem[j];
#pragma unroll
            for (int u = 0; u < QPT; ++u) {
                const float dot = __builtin_fmaf(a2[u], b.z,
                                  __builtin_fmaf(a1[u], b.y, mul_rn(a0[u], b.x)));
                const float t = __builtin_fmaf(-2.0f, dot, b.w);  // bw - 2*dot
                d0[u] = fminf(d0[u], t);
            }
        }
    }

#pragma unroll
    for (int u = 0; u < QPT; ++u) {
        const int qi = (blockIdx.x * QPT + u) * BLOCK + tid;
        smin[(size_t)qi * S + s] = an[u] + d0[u];   // fold an back in once
    }
}

// Pass 2: ONE WAVE PER QUERY, all in-register:
//  A) lane s reads slice s's (approx) min — coalesced 256 B/wave;
//     butterfly-reduce the 3 smallest -> g2 = 3rd-smallest slice-min.
//  B) mask = ballot(v <= g2 + DELTA): covers every slice containing a true
//     top-3 member (g2 >= true 3rd-smallest sq; DELTA >> deferred-an
//     drift). popcount ~3-4. Lanes cooperatively rescan those slices with
//     lane-coalesced loads and the EXACT reference-rounded pair_sq;
//     per-lane strict-< top-3 (ascending-idx stream) then a lexicographic
//     butterfly merge == lax.top_k exactly.
//  C) lane 0: rounding-exact weights + flow gather + store.
__global__ __launch_bounds__(BLOCK, 4) void rescan_kernel(
    const float* __restrict__ q, const float* __restrict__ r,
    const float* __restrict__ smin, const float* __restrict__ flow,
    float* __restrict__ out, int N, int refsPerSlice)
{
    const int lane = threadIdx.x & 63;
    const int qi   = blockIdx.x * (BLOCK / 64) + (threadIdx.x >> 6);

    const float a0 = q[qi * 3 + 0];
    const float a1 = q[qi * 3 + 1];
    const float a2 = q[qi * 3 + 2];
    const float an = sumsq3(a0, a1, a2);

    // --- A: coalesced min load + butterfly 3-smallest reduce ---
    const float v = smin[(size_t)qi * S + lane];
    float g0 = v, g1 = __builtin_inff(), g2 = __builtin_inff();
#pragma unroll
    for (int m = 1; m < 64; m <<= 1) {
        const float e0 = __shfl_xor(g0, m);
        const float e1 = __shfl_xor(g1, m);
        const float e2 = __shfl_xor(g2, m);
        val3_push(g0, g1, g2, e0);
        val3_push(g0, g1, g2, e1);
        val3_push(g0, g1, g2, e2);
    }

    unsigned long long mask = __ballot(v <= g2 + DELTA);

    // --- B: cooperative exact rescan of contributing slices ---
    float d0 = __builtin_inff(), d1 = __builtin_inff(), d2 = __builtin_inff();
    int   i0 = 0x7fffffff, i1 = 0x7fffffff, i2 = 0x7fffffff;
    const int K = refsPerSlice >> 6;       // refs per lane per slice

    while (mask) {
        const int s = (int)__builtin_ctzll(mask);
        mask &= mask - 1;
        const int base = s * refsPerSlice;
        for (int k = 0; k < K; ++k) {
            const int idx = base + lane + (k << 6);   // ascending per lane
            const float b0 = r[3 * idx + 0];
            const float b1 = r[3 * idx + 1];
            const float b2 = r[3 * idx + 2];
            const float bw = sumsq3(b0, b1, b2);
            const float sq = pair_sq(a0, a1, a2, an, b0, b1, b2, bw);
            const bool c0 = sq < d0;
            const bool c1 = sq < d1;
            const bool c2 = sq < d2;
            i2 = c1 ? i1 : (c2 ? idx : i2);
            d2 = c1 ? d1 : (c2 ? sq  : d2);
            i1 = c0 ? i0 : (c1 ? idx : i1);
            d1 = c0 ? d0 : (c1 ? sq  : d1);
            i0 = c0 ? idx : i0;
            d0 = c0 ? sq  : d0;
        }
    }

    // lexicographic butterfly merge across the 64 lanes
#pragma unroll
    for (int m = 1; m < 64; m <<= 1) {
        const float e0 = __shfl_xor(d0, m);
        const float e1 = __shfl_xor(d1, m);
        const float e2 = __shfl_xor(d2, m);
        const int   j0 = __shfl_xor(i0, m);
        const int   j1 = __shfl_xor(i1, m);
        const int   j2 = __shfl_xor(i2, m);
        lex3_push(d0, d1, d2, i0, i1, i2, e0, j0);
        lex3_push(d0, d1, d2, i0, i1, i2, e1, j1);
        lex3_push(d0, d1, d2, i0, i1, i2, e2, j2);
    }

    // --- C: epilogue (rounding-exact, matches reference op order) ---
    if (lane == 0) {
        const float t0 = sqrtf(fmaxf(d0, 1e-12f));
        const float t1 = sqrtf(fmaxf(d1, 1e-12f));
        const float t2 = sqrtf(fmaxf(d2, 1e-12f));
        const float w0r = 1.0f / add_rn(t0, 1e-8f);
        const float w1r = 1.0f / add_rn(t1, 1e-8f);
        const float w2r = 1.0f / add_rn(t2, 1e-8f);
        const float wsum = add_rn(add_rn(w0r, w1r), w2r);
        const float w0 = w0r / wsum;
        const float w1 = w1r / wsum;
        const float w2 = w2r / wsum;

        const float f00 = flow[3 * i0 + 0], f01 = flow[3 * i0 + 1], f02 = flow[3 * i0 + 2];
        const float f10 = flow[3 * i1 + 0], f11 = flow[3 * i1 + 1], f12 = flow[3 * i1 + 2];
        const float f20 = flow[3 * i2 + 0], f21 = flow[3 * i2 + 1], f22 = flow[3 * i2 + 2];

        out[qi * 3 + 0] = add_rn(add_rn(mul_rn(w0, f00), mul_rn(w1, f10)), mul_rn(w2, f20));
        out[qi * 3 + 1] = add_rn(add_rn(mul_rn(w0, f01), mul_rn(w1, f11)), mul_rn(w2, f21));
        out[qi * 3 + 2] = add_rn(add_rn(mul_rn(w0, f02), mul_rn(w1, f12)), mul_rn(w2, f22));
    }
}

extern "C" void kernel_launch(void* const* d_in, const int* in_sizes, int n_in,
                              void* d_out, int out_size, void* d_ws, size_t ws_size,
                              hipStream_t stream) {
    const float* q    = (const float*)d_in[0];
    const float* r    = (const float*)d_in[1];
    const float* flow = (const float*)d_in[2];
    // d_in[3] is k (==3), hard-coded.

    const int N = in_sizes[0] / 3;
    const int M = in_sizes[1] / 3;

    // ws layout: [smin: N*S floats], transposed [qi][s]
    const int refsPerSlice = M / S;
    float* smin = (float*)d_ws;
    (void)ws_size;

    dim3 grid1(N / (BLOCK * QPT), S);
    values_kernel<<<grid1, BLOCK, 0, stream>>>(q, r, smin, N, refsPerSlice);

    rescan_kernel<<<N / (BLOCK / 64), BLOCK, 0, stream>>>(
        q, r, smin, flow, (float*)d_out, N, refsPerSlice);
}

// Round 10
// 107.046 us; speedup vs baseline: 1.4916x; 1.0356x over previous
//
#include <hip/hip_runtime.h>
#include <math.h>

#define BLOCK 256
#define QPT   4      // queries per thread in the values pass (4 => 4 blocks/CU)
#define CHUNK 512    // max refs staged per LDS chunk (8 KB of float4)
#define S     64     // slices == wave width (one ballot bit per slice)
#define DELTA 0.05f  // conservative slack for deferred-an slice mins (see below)

// Rounding-exact helpers: match numpy's mul-then-add rounding exactly.
__device__ __forceinline__ float mul_rn(float a, float b) {
#pragma clang fp contract(off)
    return a * b;
}
__device__ __forceinline__ float add_rn(float a, float b) {
#pragma clang fp contract(off)
    return a + b;
}
__device__ __forceinline__ float sumsq3(float x, float y, float z) {
    return add_rn(add_rn(mul_rn(x, x), mul_rn(y, y)), mul_rn(z, z));
}
__device__ __forceinline__ float med3f(float a, float b, float c) {
    return __builtin_amdgcn_fmed3f(a, b, c);
}
// EXACT sq = (||a||^2 + ||b||^2) - 2*dot — bit-matches the reference
// (used in the rescan where indices are selected).
__device__ __forceinline__ float pair_sq(float a0, float a1, float a2, float an,
                                         float bx, float by, float bz, float bw) {
    const float dot = __builtin_fmaf(a2, bz,
                      __builtin_fmaf(a1, by, mul_rn(a0, bx)));
    return __builtin_fmaf(-2.0f, dot, add_rn(an, bw));
}

// In-place top-3 VALUES update: write order d2 <- d1 <- d0 needs NO temps.
__device__ __forceinline__ void val3_push(float& d0, float& d1, float& d2, float v) {
    d2 = med3f(d1, d2, v);
    d1 = med3f(d0, d1, v);
    d0 = fminf(d0, v);
}

// Lexicographic (sq, idx) top-3 insert — matches lax.top_k stability.
__device__ __forceinline__ void lex3_push(float& d0, float& d1, float& d2,
                                          int& i0, int& i1, int& i2,
                                          float sq, int idx) {
    const bool l0 = (sq < d0) || (sq == d0 && idx < i0);
    const bool l1 = (sq < d1) || (sq == d1 && idx < i1);
    const bool l2 = (sq < d2) || (sq == d2 && idx < i2);
    i2 = l1 ? i1 : (l2 ? idx : i2);
    d2 = l1 ? d1 : (l2 ? sq  : d2);
    i1 = l0 ? i0 : (l1 ? idx : i1);
    d1 = l0 ? d0 : (l1 ? sq  : d1);
    i0 = l0 ? idx : i0;
    d0 = l0 ? sq  : d0;
}

// Stage cnt refs (cnt % 4 == 0, start % 4 == 0) into smem as (x,y,z,||b||^2).
__device__ __forceinline__ void stage_chunk(const float* __restrict__ r,
                                            int start, int cnt,
                                            float4* __restrict__ smem) {
    const int t = threadIdx.x;
    if (t < (cnt >> 2)) {
        const float4* p = (const float4*)(r + (size_t)(start + t * 4) * 3);
        const float4 A = p[0], B = p[1], C = p[2];
        smem[t * 4 + 0] = make_float4(A.x, A.y, A.z, sumsq3(A.x, A.y, A.z));
        smem[t * 4 + 1] = make_float4(A.w, B.x, B.y, sumsq3(A.w, B.x, B.y));
        smem[t * 4 + 2] = make_float4(B.z, B.w, C.x, sumsq3(B.z, B.w, C.x));
        smem[t * 4 + 3] = make_float4(C.y, C.z, C.w, sumsq3(C.y, C.z, C.w));
    }
}

// Pass 1: per (query, slice) approximate min of sq, `an` deferred out of
// the loop (min_j[(an+bw)-2dot] = an + min_j[bw-2dot] + O(5e-3) drift,
// absorbed by DELTA in pass 2). Hot loop: 5 VALU/pair. QPT=4 -> 1024
// blocks = 4 blocks/CU = 4 waves/SIMD for latency hiding (QPT=8's 2
// waves/SIMD stalled; R6/R8 evidence).
__global__ __launch_bounds__(BLOCK, 4) void values_kernel(
    const float* __restrict__ q, const float* __restrict__ r,
    float* __restrict__ smin, int N, int refsPerSlice)
{
    __shared__ float4 smem[CHUNK];
    const int tid = threadIdx.x;
    const int s   = blockIdx.y;
    const int start = s * refsPerSlice;

    float a0[QPT], a1[QPT], a2[QPT], an[QPT], d0[QPT];
#pragma unroll
    for (int u = 0; u < QPT; ++u) {
        const int qi = (blockIdx.x * QPT + u) * BLOCK + tid;
        a0[u] = q[qi * 3 + 0];
        a1[u] = q[qi * 3 + 1];
        a2[u] = q[qi * 3 + 2];
        an[u] = sumsq3(a0[u], a1[u], a2[u]);
        d0[u] = __builtin_inff();
    }

    for (int coff = 0; coff < refsPerSlice; coff += CHUNK) {
        const int cnt = min(CHUNK, refsPerSlice - coff);
        __syncthreads();
        stage_chunk(r, start + coff, cnt, smem);
        __syncthreads();
#pragma unroll 8
        for (int j = 0; j < cnt; ++j) {
            const float4 b = smem[j];
#pragma unroll
            for (int u = 0; u < QPT; ++u) {
                const float dot = __builtin_fmaf(a2[u], b.z,
                                  __builtin_fmaf(a1[u], b.y, mul_rn(a0[u], b.x)));
                const float t = __builtin_fmaf(-2.0f, dot, b.w);  // bw - 2*dot
                d0[u] = fminf(d0[u], t);
            }
        }
    }

#pragma unroll
    for (int u = 0; u < QPT; ++u) {
        const int qi = (blockIdx.x * QPT + u) * BLOCK + tid;
        smin[(size_t)qi * S + s] = an[u] + d0[u];   // fold an back in once
    }
}

// Pass 2: ONE WAVE PER QUERY, all in-register:
//  A) lane s reads slice s's (approx) min — coalesced 256 B/wave;
//     butterfly-reduce the 3 smallest -> g2 = 3rd-smallest slice-min.
//  B) mask = ballot(v <= g2 + DELTA): covers every slice containing a true
//     top-3 member (g2 >= true 3rd-smallest sq; DELTA >> deferred-an
//     drift). popcount ~3-4. Lanes cooperatively rescan those slices with
//     lane-coalesced loads and the EXACT reference-rounded pair_sq;
//     per-lane strict-< top-3 (ascending-idx stream) then a lexicographic
//     butterfly merge == lax.top_k exactly.
//  C) lane 0: rounding-exact weights + flow gather + store.
__global__ __launch_bounds__(BLOCK, 4) void rescan_kernel(
    const float* __restrict__ q, const float* __restrict__ r,
    const float* __restrict__ smin, const float* __restrict__ flow,
    float* __restrict__ out, int N, int refsPerSlice)
{
    const int lane = threadIdx.x & 63;
    const int qi   = blockIdx.x * (BLOCK / 64) + (threadIdx.x >> 6);

    const float a0 = q[qi * 3 + 0];
    const float a1 = q[qi * 3 + 1];
    const float a2 = q[qi * 3 + 2];
    const float an = sumsq3(a0, a1, a2);

    // --- A: coalesced min load + butterfly 3-smallest reduce ---
    const float v = smin[(size_t)qi * S + lane];
    float g0 = v, g1 = __builtin_inff(), g2 = __builtin_inff();
#pragma unroll
    for (int m = 1; m < 64; m <<= 1) {
        const float e0 = __shfl_xor(g0, m);
        const float e1 = __shfl_xor(g1, m);
        const float e2 = __shfl_xor(g2, m);
        val3_push(g0, g1, g2, e0);
        val3_push(g0, g1, g2, e1);
        val3_push(g0, g1, g2, e2);
    }

    unsigned long long mask = __ballot(v <= g2 + DELTA);

    // --- B: cooperative exact rescan of contributing slices ---
    float d0 = __builtin_inff(), d1 = __builtin_inff(), d2 = __builtin_inff();
    int   i0 = 0x7fffffff, i1 = 0x7fffffff, i2 = 0x7fffffff;
    const int K = refsPerSlice >> 6;       // refs per lane per slice

    while (mask) {
        const int s = (int)__builtin_ctzll(mask);
        mask &= mask - 1;
        const int base = s * refsPerSlice;
        for (int k = 0; k < K; ++k) {
            const int idx = base + lane + (k << 6);   // ascending per lane
            const float b0 = r[3 * idx + 0];
            const float b1 = r[3 * idx + 1];
            const float b2 = r[3 * idx + 2];
            const float bw = sumsq3(b0, b1, b2);
            const float sq = pair_sq(a0, a1, a2, an, b0, b1, b2, bw);
            const bool c0 = sq < d0;
            const bool c1 = sq < d1;
            const bool c2 = sq < d2;
            i2 = c1 ? i1 : (c2 ? idx : i2);
            d2 = c1 ? d1 : (c2 ? sq  : d2);
            i1 = c0 ? i0 : (c1 ? idx : i1);
            d1 = c0 ? d0 : (c1 ? sq  : d1);
            i0 = c0 ? idx : i0;
            d0 = c0 ? sq  : d0;
        }
    }

    // lexicographic butterfly merge across the 64 lanes
#pragma unroll
    for (int m = 1; m < 64; m <<= 1) {
        const float e0 = __shfl_xor(d0, m);
        const float e1 = __shfl_xor(d1, m);
        const float e2 = __shfl_xor(d2, m);
        const int   j0 = __shfl_xor(i0, m);
        const int   j1 = __shfl_xor(i1, m);
        const int   j2 = __shfl_xor(i2, m);
        lex3_push(d0, d1, d2, i0, i1, i2, e0, j0);
        lex3_push(d0, d1, d2, i0, i1, i2, e1, j1);
        lex3_push(d0, d1, d2, i0, i1, i2, e2, j2);
    }

    // --- C: epilogue (rounding-exact, matches reference op order) ---
    if (lane == 0) {
        const float t0 = sqrtf(fmaxf(d0, 1e-12f));
        const float t1 = sqrtf(fmaxf(d1, 1e-12f));
        const float t2 = sqrtf(fmaxf(d2, 1e-12f));
        const float w0r = 1.0f / add_rn(t0, 1e-8f);
        const float w1r = 1.0f / add_rn(t1, 1e-8f);
        const float w2r = 1.0f / add_rn(t2, 1e-8f);
        const float wsum = add_rn(add_rn(w0r, w1r), w2r);
        const float w0 = w0r / wsum;
        const float w1 = w1r / wsum;
        const float w2 = w2r / wsum;

        const float f00 = flow[3 * i0 + 0], f01 = flow[3 * i0 + 1], f02 = flow[3 * i0 + 2];
        const float f10 = flow[3 * i1 + 0], f11 = flow[3 * i1 + 1], f12 = flow[3 * i1 + 2];
        const float f20 = flow[3 * i2 + 0], f21 = flow[3 * i2 + 1], f22 = flow[3 * i2 + 2];

        out[qi * 3 + 0] = add_rn(add_rn(mul_rn(w0, f00), mul_rn(w1, f10)), mul_rn(w2, f20));
        out[qi * 3 + 1] = add_rn(add_rn(mul_rn(w0, f01), mul_rn(w1, f11)), mul_rn(w2, f21));
        out[qi * 3 + 2] = add_rn(add_rn(mul_rn(w0, f02), mul_rn(w1, f12)), mul_rn(w2, f22));
    }
}

extern "C" void kernel_launch(void* const* d_in, const int* in_sizes, int n_in,
                              void* d_out, int out_size, void* d_ws, size_t ws_size,
                              hipStream_t stream) {
    const float* q    = (const float*)d_in[0];
    const float* r    = (const float*)d_in[1];
    const float* flow = (const float*)d_in[2];
    // d_in[3] is k (==3), hard-coded.

    const int N = in_sizes[0] / 3;
    const int M = in_sizes[1] / 3;

    // ws layout: [smin: N*S floats], transposed [qi][s]
    const int refsPerSlice = M / S;
    float* smin = (float*)d_ws;
    (void)ws_size;

    dim3 grid1(N / (BLOCK * QPT), S);
    values_kernel<<<grid1, BLOCK, 0, stream>>>(q, r, smin, N, refsPerSlice);

    rescan_kernel<<<N / (BLOCK / 64), BLOCK, 0, stream>>>(
        q, r, smin, flow, (float*)d_out, N, refsPerSlice);
}